// Round 8
// baseline (210.496 us; speedup 1.0000x reference)
//
#include <hip/hip_runtime.h>

// entmax-1.5 over last axis of (1024, 255, 512) fp32.
// tau solve: fused(shift + Michelot quadratic @ tau=-1) + 4 Newton.
// Layout: 16 lanes/row, 4 rows/wave, 32 elems/lane as v2f (packed fp32).
// R8: 2-way ILP — each wave solves TWO independent row-groups (A,B) with all
// passes written pairwise, so the two dependency chains interleave and fill
// each other's DPP-hazard / rcp / VMEM stalls. Persistent waves, 5 pair-iters.

typedef float v2f __attribute__((ext_vector_type(2)));
typedef float v4f __attribute__((ext_vector_type(4)));

constexpr int N_FEAT  = 512;
constexpr int NBLOCKS = 1632;
constexpr int NWAVES  = NBLOCKS * 4;      // 6528 waves; 65280 row-groups total
constexpr int NPAIR   = 5;                // 10 row-groups per wave, 2 per iter
constexpr float TAU_HI = -0.044194174f;   // -1/sqrt(512) >= tau* always

template <int CTRL>
__device__ __forceinline__ float dpp_add(float v) {
    int p = __builtin_amdgcn_update_dpp(0, __float_as_int(v), CTRL, 0xF, 0xF, true);
    return v + __int_as_float(p);
}
template <int CTRL>
__device__ __forceinline__ float dpp_max(float v) {
    int p = __builtin_amdgcn_update_dpp(0, __float_as_int(v), CTRL, 0xF, 0xF, true);
    return fmaxf(v, __int_as_float(p));
}
__device__ __forceinline__ float reduce16_add(float v) {
    v = dpp_add<0xB1>(v);   // quad_perm xor1
    v = dpp_add<0x4E>(v);   // quad_perm xor2
    v = dpp_add<0x141>(v);  // row_half_mirror
    v = dpp_add<0x140>(v);  // row_mirror
    return v;
}
__device__ __forceinline__ float reduce16_max(float v) {
    v = dpp_max<0xB1>(v);
    v = dpp_max<0x4E>(v);
    v = dpp_max<0x141>(v);
    v = dpp_max<0x140>(v);
    return v;
}

__device__ __forceinline__ void load16(const float* __restrict__ p, v2f (&b)[16]) {
#pragma unroll
    for (int k = 0; k < 8; ++k) {
        v4f v = *reinterpret_cast<const v4f*>(p + k * 64);
        b[2 * k]     = (v2f){v.x, v.y};
        b[2 * k + 1] = (v2f){v.z, v.w};
    }
}

__global__ __launch_bounds__(256) void entmax15_kernel(const float* __restrict__ in,
                                                       float* __restrict__ out) {
    const int wave = threadIdx.x >> 6;
    const int lane = threadIdx.x & 63;
    const int g    = lane >> 4;   // row within row-group (0..3)
    const int t    = lane & 15;   // lane within 16-lane row group

    const int wid = blockIdx.x * 4 + wave;               // 0..NWAVES-1
    size_t off = (size_t)(wid * 4 + g) * N_FEAT + t * 4;
    const size_t step = (size_t)NWAVES * 4 * N_FEAT;     // row-group stride

    const float* rpA = in  + off;
    float*       opA = out + off;

    const v2f zero2 = {0.0f, 0.0f};
    const v2f one2  = {1.0f, 1.0f};

#pragma unroll
    for (int s = 0; s < NPAIR; ++s) {
        const float* rpB = rpA + step;
        float*       opB = opA + step;

        v2f xa[16], xb[16];
        load16(rpA, xa);
        load16(rpB, xb);

        // ---- pass 1: row max (pairwise; two independent DPP chains) ----
        v2f ma = xa[0], mb = xb[0];
#pragma unroll
        for (int k = 1; k < 16; ++k) {
            ma = __builtin_elementwise_max(ma, xa[k]);
            mb = __builtin_elementwise_max(mb, xb[k]);
        }
        const float mA = reduce16_max(fmaxf(ma.x, ma.y)) * 0.5f;
        const float mB = reduce16_max(fmaxf(mb.x, mb.y)) * 0.5f;
        const v2f mA2 = {mA, mA}, mB2 = {mB, mB};

        // ---- pass 2: fused shift + Michelot stats at tau = -1 ----
        v2f s1a = zero2, s2a = zero2, ca = zero2;
        v2f s1b = zero2, s2b = zero2, cb = zero2;
#pragma unroll
        for (int k = 0; k < 16; ++k) {
            v2f x = xa[k] * 0.5f - mA2;
            xa[k] = x;
            v2f d = __builtin_elementwise_max(x + one2, zero2);
            s1a += d; s2a += d * d;
            ca  += __builtin_elementwise_min(d * 1e12f, one2);

            v2f y = xb[k] * 0.5f - mB2;
            xb[k] = y;
            v2f e = __builtin_elementwise_max(y + one2, zero2);
            s1b += e; s2b += e * e;
            cb  += __builtin_elementwise_min(e * 1e12f, one2);
        }
        float s1A = reduce16_add(s1a.x + s1a.y);
        float s1B = reduce16_add(s1b.x + s1b.y);
        float s2A = reduce16_add(s2a.x + s2a.y);
        float s2B = reduce16_add(s2b.x + s2b.y);
        float kA  = reduce16_add(ca.x + ca.y);
        float kB  = reduce16_add(cb.x + cb.y);

        float discA = fmaxf(fmaf(s1A, s1A, -kA * (s2A - 1.0f)), 0.0f);
        float discB = fmaxf(fmaf(s1B, s1B, -kB * (s2B - 1.0f)), 0.0f);
        float tauA = -1.0f + (s1A - __builtin_amdgcn_sqrtf(discA)) * __builtin_amdgcn_rcpf(kA);
        float tauB = -1.0f + (s1B - __builtin_amdgcn_sqrtf(discB)) * __builtin_amdgcn_rcpf(kB);
        tauA = fminf(fmaxf(tauA, -1.0f), TAU_HI);
        tauB = fminf(fmaxf(tauB, -1.0f), TAU_HI);

        // ---- Newton polish x4 (pairwise) ----
#pragma unroll
        for (int it = 0; it < 4; ++it) {
            v2f tA2 = {tauA, tauA}, tB2 = {tauB, tauB};
            v2f aA = zero2, bA = zero2, aB = zero2, bB = zero2;
#pragma unroll
            for (int k = 0; k < 16; ++k) {
                v2f d = __builtin_elementwise_max(xa[k] - tA2, zero2);
                aA += d; bA = (v2f){fmaf(d.x, d.x, bA.x), fmaf(d.y, d.y, bA.y)};
                v2f e = __builtin_elementwise_max(xb[k] - tB2, zero2);
                aB += e; bB = (v2f){fmaf(e.x, e.x, bB.x), fmaf(e.y, e.y, bB.y)};
            }
            float S1A = reduce16_add(aA.x + aA.y);
            float S1B = reduce16_add(aB.x + aB.y);
            float S2A = reduce16_add(bA.x + bA.y);
            float S2B = reduce16_add(bB.x + bB.y);
            tauA += (S2A - 1.0f) * __builtin_amdgcn_rcpf(2.0f * S1A);
            tauB += (S2B - 1.0f) * __builtin_amdgcn_rcpf(2.0f * S1B);
            tauA = fminf(fmaxf(tauA, -1.0f), TAU_HI);
            tauB = fminf(fmaxf(tauB, -1.0f), TAU_HI);
        }

        // ---- output: relu(x - tau)^2, nontemporal stores ----
        v2f tA2 = {tauA, tauA}, tB2 = {tauB, tauB};
#pragma unroll
        for (int k = 0; k < 8; ++k) {
            v2f d0 = __builtin_elementwise_max(xa[2 * k]     - tA2, zero2);
            v2f d1 = __builtin_elementwise_max(xa[2 * k + 1] - tA2, zero2);
            d0 *= d0; d1 *= d1;
            v4f oA = {d0.x, d0.y, d1.x, d1.y};
            __builtin_nontemporal_store(oA, reinterpret_cast<v4f*>(opA + k * 64));

            v2f e0 = __builtin_elementwise_max(xb[2 * k]     - tB2, zero2);
            v2f e1 = __builtin_elementwise_max(xb[2 * k + 1] - tB2, zero2);
            e0 *= e0; e1 *= e1;
            v4f oB = {e0.x, e0.y, e1.x, e1.y};
            __builtin_nontemporal_store(oB, reinterpret_cast<v4f*>(opB + k * 64));
        }

        rpA += 2 * step;
        opA += 2 * step;
    }
}

extern "C" void kernel_launch(void* const* d_in, const int* in_sizes, int n_in,
                              void* d_out, int out_size, void* d_ws, size_t ws_size,
                              hipStream_t stream) {
    const float* in  = (const float*)d_in[0];
    float*       out = (float*)d_out;
    entmax15_kernel<<<dim3(NBLOCKS), dim3(256), 0, stream>>>(in, out);
}

// Round 9
// 201.586 us; speedup vs baseline: 1.0442x; 1.0442x over previous
//
#include <hip/hip_runtime.h>

// entmax-1.5 over last axis of (1024, 255, 512) fp32.
// R9: fully-contiguous memory instructions. Each wave owns 4 consecutive rows
// (8 KB); load/store k covers 1 KB contiguous (64 lanes x 16 B), so lane l's
// register pair k holds row k>>1. Per-row reductions are 6-step full-wave DPP
// (4 in-row steps + row_bcast15 + row_bcast31) + readlane(63) -> scalar.
// tau solve: 2 Michelot quadratic passes (bracketing tau*) + 2 Newton.

typedef float v2f __attribute__((ext_vector_type(2)));
typedef float v4f __attribute__((ext_vector_type(4)));

constexpr int N_FEAT = 512;
constexpr long long N_ROWS = 1024LL * 255LL;   // 261120
constexpr int ROWS_PER_BLOCK = 16;             // 256 threads = 4 waves x 4 rows
constexpr float TAU_HI = -0.044194174f;        // -1/sqrt(512) >= tau* always

template <int CTRL>
__device__ __forceinline__ float dpp_add(float v) {
    int p = __builtin_amdgcn_update_dpp(0, __float_as_int(v), CTRL, 0xF, 0xF, true);
    return v + __int_as_float(p);
}
template <int CTRL>
__device__ __forceinline__ float dpp_max(float v) {
    int p = __builtin_amdgcn_update_dpp(0, __float_as_int(v), CTRL, 0xF, 0xF, true);
    return fmaxf(v, __int_as_float(p));
}

// Full 64-lane reduction -> scalar (uniform) via readlane(63).
__device__ __forceinline__ float red64_add(float v) {
    v = dpp_add<0xB1>(v);    // quad_perm xor1
    v = dpp_add<0x4E>(v);    // quad_perm xor2
    v = dpp_add<0x141>(v);   // row_half_mirror
    v = dpp_add<0x140>(v);   // row_mirror -> each 16-lane row holds its total
    { int p = __builtin_amdgcn_update_dpp(0, __float_as_int(v), 0x142, 0xa, 0xF, false);
      v += __int_as_float(p); }   // row_bcast15: rows 1,3 += rows 0,2 totals
    { int p = __builtin_amdgcn_update_dpp(0, __float_as_int(v), 0x143, 0xc, 0xF, false);
      v += __int_as_float(p); }   // row_bcast31: rows 2,3 += lanes0-31 total
    return __int_as_float(__builtin_amdgcn_readlane(__float_as_int(v), 63));
}
__device__ __forceinline__ float red64_max(float v) {
    const int NEG_INF = (int)0xff800000u;
    v = dpp_max<0xB1>(v);
    v = dpp_max<0x4E>(v);
    v = dpp_max<0x141>(v);
    v = dpp_max<0x140>(v);
    { int p = __builtin_amdgcn_update_dpp(NEG_INF, __float_as_int(v), 0x142, 0xa, 0xF, false);
      v = fmaxf(v, __int_as_float(p)); }
    { int p = __builtin_amdgcn_update_dpp(NEG_INF, __float_as_int(v), 0x143, 0xc, 0xF, false);
      v = fmaxf(v, __int_as_float(p)); }
    return __int_as_float(__builtin_amdgcn_readlane(__float_as_int(v), 63));
}

__global__ __launch_bounds__(256) void entmax15_kernel(const float* __restrict__ in,
                                                       float* __restrict__ out) {
    const int wave = threadIdx.x >> 6;
    const int lane = threadIdx.x & 63;

    const size_t tileBase = ((size_t)blockIdx.x * ROWS_PER_BLOCK + wave * 4) * N_FEAT;
    const float* rp = in  + tileBase + lane * 4;
    float*       op = out + tileBase + lane * 4;

    // Contiguous 1KB loads: x2[2k],x2[2k+1] belong to row k>>1 (x2[j]: row j>>2).
    v2f x2[16];
#pragma unroll
    for (int k = 0; k < 8; ++k) {
        v4f v = *reinterpret_cast<const v4f*>(rp + k * 256);
        x2[2 * k]     = (v2f){v.x, v.y};
        x2[2 * k + 1] = (v2f){v.z, v.w};
    }

    const v2f zero2 = {0.0f, 0.0f};
    const v2f one2  = {1.0f, 1.0f};

    // Per-row max of raw logits -> m[r] = max/2; shift x = x*0.5 - m[r].
    float m[4], tau[4];
#pragma unroll
    for (int r = 0; r < 4; ++r) {
        v2f mm = __builtin_elementwise_max(
                     __builtin_elementwise_max(x2[4 * r], x2[4 * r + 1]),
                     __builtin_elementwise_max(x2[4 * r + 2], x2[4 * r + 3]));
        m[r] = red64_max(fmaxf(mm.x, mm.y)) * 0.5f;
    }
#pragma unroll
    for (int r = 0; r < 4; ++r) {
        const v2f mr = {m[r], m[r]};
#pragma unroll
        for (int j = 0; j < 4; ++j)
            x2[4 * r + j] = x2[4 * r + j] * 0.5f - mr;
        tau[r] = -1.0f;
    }

    // 2 Michelot quadratic passes: solve sum_{x>tau}(x - tau - delta)^2 = 1.
    // Pass 1 lands >= tau*, pass 2 <= tau* (bracketing, rapidly exact).
#pragma unroll
    for (int pass = 0; pass < 2; ++pass) {
#pragma unroll
        for (int r = 0; r < 4; ++r) {
            const v2f tr = {tau[r], tau[r]};
            v2f s1v = zero2, s2v = zero2, cv = zero2;
#pragma unroll
            for (int j = 0; j < 4; ++j) {
                v2f d = __builtin_elementwise_max(x2[4 * r + j] - tr, zero2);
                s1v += d;
                s2v += d * d;
                cv  += __builtin_elementwise_min(d * 1e12f, one2);
            }
            float s1 = red64_add(s1v.x + s1v.y);
            float s2 = red64_add(s2v.x + s2v.y);
            float c  = red64_add(cv.x + cv.y);
            float disc = fmaxf(fmaf(s1, s1, -c * (s2 - 1.0f)), 0.0f);
            float t = tau[r] + (s1 - __builtin_amdgcn_sqrtf(disc)) * __builtin_amdgcn_rcpf(c);
            tau[r] = fminf(fmaxf(t, -1.0f), TAU_HI);
        }
    }

    // 2 Newton polish steps: f(tau) = sum relu(x-tau)^2 = 1.
#pragma unroll
    for (int it = 0; it < 2; ++it) {
#pragma unroll
        for (int r = 0; r < 4; ++r) {
            const v2f tr = {tau[r], tau[r]};
            v2f a = zero2, b = zero2;
#pragma unroll
            for (int j = 0; j < 4; ++j) {
                v2f d = __builtin_elementwise_max(x2[4 * r + j] - tr, zero2);
                a += d;
                b = (v2f){fmaf(d.x, d.x, b.x), fmaf(d.y, d.y, b.y)};
            }
            float S1 = red64_add(a.x + a.y);
            float S2 = red64_add(b.x + b.y);
            float t = tau[r] + (S2 - 1.0f) * __builtin_amdgcn_rcpf(2.0f * S1);
            tau[r] = fminf(fmaxf(t, -1.0f), TAU_HI);
        }
    }

    // out = relu(x - tau)^2; contiguous 1KB nontemporal stores.
#pragma unroll
    for (int k = 0; k < 8; ++k) {
        const int r = k >> 1;
        const v2f tr = {tau[r], tau[r]};
        v2f d0 = __builtin_elementwise_max(x2[2 * k]     - tr, zero2);
        v2f d1 = __builtin_elementwise_max(x2[2 * k + 1] - tr, zero2);
        d0 *= d0;
        d1 *= d1;
        v4f o = {d0.x, d0.y, d1.x, d1.y};
        __builtin_nontemporal_store(o, reinterpret_cast<v4f*>(op + k * 256));
    }
}

extern "C" void kernel_launch(void* const* d_in, const int* in_sizes, int n_in,
                              void* d_out, int out_size, void* d_ws, size_t ws_size,
                              hipStream_t stream) {
    const float* in  = (const float*)d_in[0];
    float*       out = (float*)d_out;
    const unsigned nblocks = (unsigned)(N_ROWS / ROWS_PER_BLOCK);  // 16320
    entmax15_kernel<<<dim3(nblocks), dim3(256), 0, stream>>>(in, out);
}